// Round 4
// baseline (86408.972 us; speedup 1.0000x reference)
//
#include <hip/hip_runtime.h>
#include <cstdint>
#include <cmath>

#define FEAT 256
#define SEQ 2048
#define NEG_BIG -10000.0f
#define MIN_SEG 3.0f

#define NSLICE 8          // gate-row slices (32 features each)
#define NB 2              // batches per group
#define NGRP 32           // BS / NB
#define FPS 32            // features per slice
#define JCOLS 128         // 4 gates * FPS rows per slice
#define KTOT 512          // 256 h + 256 x

// ws layout (floats). Sync region = 41472 floats = 162 KB.
#define FLAGS_FLOATS (NGRP * NSLICE * 32)          // uint flags, 128B apart
#define HX_OFF   FLAGS_FLOATS                      // [2][NGRP][NB][FEAT]
#define HX_FLOATS (2 * NGRP * NB * FEAT)
#define POL_OFF  (HX_OFF + HX_FLOATS)              // [2][NGRP][NSLICE][4]
#define POL_FLOATS (2 * NGRP * NSLICE * 4)
#define SYNC_FLOATS (POL_OFF + POL_FLOATS)

__global__ __launch_bounds__(512, 1) void seq_kernel(
    const float* __restrict__ x,
    const float* __restrict__ W_ih, const float* __restrict__ W_hh,
    const float* __restrict__ b_ih, const float* __restrict__ b_hh,
    const float* __restrict__ Wp, const float* __restrict__ bp,
    float* __restrict__ ws, float* __restrict__ out_b, float* __restrict__ out_sel)
{
    const int bid = blockIdx.x;
    const int s   = bid >> 5;        // slice 0..7
    const int p   = bid & 31;        // batch-group 0..31 (bid%8 = p%8 -> all 8
                                     // slice-blocks of a group on one XCD)
    const int tid = threadIdx.x;
    const int kc  = tid & 31;        // k-chunk 0..31 (lane bits 0..4 -> butterfly)
    const int jq  = tid >> 5;        // j-octet 0..15
    const int koff = kc * 16;        // 16-float window in [h(256); x(256)]
    const bool isH = (kc < 16);
    const int bb0 = p * NB;

    unsigned int* flags = (unsigned int*)ws + (size_t)p * (NSLICE * 32);
    float* hx  = ws + HX_OFF;
    float* pol = ws + POL_OFF;

    __shared__ float G_lds[NB][JCOLS];
    __shared__ float polbuf[NSLICE * 4];
    __shared__ float s_prev[NB];

    // ---- weight slice -> 128 registers/thread (stationary all 2048 steps) ----
    float w[16][8];
#pragma unroll
    for (int jj = 0; jj < 8; ++jj) {
        const int jcol = jq * 8 + jj;          // [g][f'] ordering
        const int g = jcol >> 5, fp = jcol & 31;
        const int j = g * FEAT + s * FPS + fp; // global gate row
        const float* r = isH ? (W_hh + (size_t)j * FEAT + koff)
                             : (W_ih + (size_t)j * (FEAT + 1) + 1 + (koff - FEAT));
#pragma unroll
        for (int kk = 0; kk < 16; ++kk) w[kk][jj] = r[kk];
    }

    const int sb_b = tid >> 5, sb_f = tid & 31;   // LSTM-update role (tid < 64)
    float biasr[4] = {}, wpbr[4] = {};
    float wp0 = 0.f, wp1 = 0.f, c_reg = 0.f;
    if (tid < 64) {
#pragma unroll
        for (int g = 0; g < 4; ++g) {
            int j = g * FEAT + s * FPS + sb_f;
            biasr[g] = b_ih[j] + b_hh[j];
            wpbr[g]  = W_ih[(size_t)j * (FEAT + 1)];   // prev-boundary column
        }
        wp0 = Wp[s * FPS + sb_f];
        wp1 = Wp[FEAT + s * FPS + sb_f];
    }
    float flagst = 0.f;                       // decision state (tid 0 / 32)
    const float bp0 = bp[0], bp1 = bp[1];
    if (tid == 0 || tid == 32) s_prev[tid >> 5] = 0.f;

    // ---- per-thread input window registers: h-part zeros, x-part = x(0) ----
    float hv0[16], hv1[16];
    if (isH) {
#pragma unroll
        for (int kk = 0; kk < 16; ++kk) { hv0[kk] = 0.f; hv1[kk] = 0.f; }
    } else {
        const float* x0 = x + ((size_t)(bb0 + 0) * SEQ + 0) * FEAT + (koff - FEAT);
        const float* x1 = x + ((size_t)(bb0 + 1) * SEQ + 0) * FEAT + (koff - FEAT);
#pragma unroll
        for (int q = 0; q < 4; ++q) {
            float4 a = *(const float4*)(x0 + q * 4);
            float4 b = *(const float4*)(x1 + q * 4);
            hv0[q*4+0]=a.x; hv0[q*4+1]=a.y; hv0[q*4+2]=a.z; hv0[q*4+3]=a.w;
            hv1[q*4+0]=b.x; hv1[q*4+1]=b.y; hv1[q*4+2]=b.z; hv1[q*4+3]=b.w;
        }
    }
    __syncthreads();

    for (int t = 0; t <= SEQ; ++t) {
        // phase 0: prefetch x(t+1) into regs (independent of recurrence;
        // issued BEFORE the spin so HBM latency hides under the whole step)
        float4 xnA[4], xnB[4];
        const bool pfx = (!isH) && (t + 1 < SEQ);
        if (pfx) {
            const float* x0 = x + ((size_t)(bb0 + 0) * SEQ + (t + 1)) * FEAT + (koff - FEAT);
            const float* x1 = x + ((size_t)(bb0 + 1) * SEQ + (t + 1)) * FEAT + (koff - FEAT);
#pragma unroll
            for (int q = 0; q < 4; ++q) {
                xnA[q] = *(const float4*)(x0 + q * 4);
                xnB[q] = *(const float4*)(x1 + q * 4);
            }
        }

        // phase 1: wait for all slices of this group to have published t-1
        if (t > 0 && tid < NSLICE) {
            int guard = 0;
            while (__hip_atomic_load(&flags[tid * 32], __ATOMIC_ACQUIRE,
                                     __HIP_MEMORY_SCOPE_AGENT) < (unsigned)t) {
                if (++guard > (1 << 22)) break;   // bug -> visible fail, not hang
            }
        }
        __syncthreads();                          // A
        __threadfence();                          // acquire: invalidate stale lines

        const int cur = t & 1;                    // buffer written this step
        const int rb  = (t + 1) & 1;              // buffer holding h(t-1)/pol(t-1)
        if (t > 0 && t < SEQ && isH) {            // h(t-1) window -> registers
            const float* h0 = &hx[(((size_t)rb * NGRP + p) * NB + 0) * FEAT + koff];
            const float* h1 = &hx[(((size_t)rb * NGRP + p) * NB + 1) * FEAT + koff];
#pragma unroll
            for (int q = 0; q < 4; ++q) {
                float4 a = *(const float4*)(h0 + q * 4);
                float4 b = *(const float4*)(h1 + q * 4);
                hv0[q*4+0]=a.x; hv0[q*4+1]=a.y; hv0[q*4+2]=a.z; hv0[q*4+3]=a.w;
                hv1[q*4+0]=b.x; hv1[q*4+1]=b.y; hv1[q*4+2]=b.z; hv1[q*4+3]=b.w;
            }
        }
        if (t > 0 && tid >= 128 && tid < 128 + NSLICE * 4)
            polbuf[tid - 128] = pol[((size_t)rb * NGRP + p) * (NSLICE * 4) + (tid - 128)];
        __syncthreads();                          // B

        // phase 2: decision for step t-1 (redundant, bit-identical in all blocks)
        if (t > 0 && (tid == 0 || tid == 32)) {
            int b = tid >> 5;
            float l0 = bp0, l1 = bp1;
#pragma unroll
            for (int ss = 0; ss < NSLICE; ++ss) {
                l0 += polbuf[ss * 4 + b * 2 + 0];
                l1 += polbuf[ss * 4 + b * 2 + 1];
            }
            if (flagst > 0.0f) l1 += NEG_BIG;
            int samp = (l1 > l0) ? 1 : 0;
            float a0 = l0 * 0.5f, a1 = l1 * 0.5f; // logits / TAU, TAU = 2
            float m = fmaxf(a0, a1);
            float lse = m + logf(expf(a0 - m) + expf(a1 - m));
            if (s == 0) {
                out_b[(size_t)(bb0 + b) * SEQ + (t - 1)]   = (float)samp;
                out_sel[(size_t)(bb0 + b) * SEQ + (t - 1)] = (samp ? a1 : a0) - lse;
            }
            flagst = (flagst > 0.0f) ? (flagst - 1.0f) : flagst;
            if (samp) flagst = MIN_SEG;
            s_prev[b] = (float)samp;
        }
        if (t == SEQ) break;

        // phase 3: K=512 matvec against register-resident weights
        float acc0[8] = {}, acc1[8] = {};
#pragma unroll
        for (int kk = 0; kk < 16; ++kk) {
            const float h0 = hv0[kk], h1 = hv1[kk];
#pragma unroll
            for (int jj = 0; jj < 8; ++jj) {
                acc0[jj] = fmaf(h0, w[kk][jj], acc0[jj]);
                acc1[jj] = fmaf(h1, w[kk][jj], acc1[jj]);
            }
        }
        // phase 4: butterfly reduce across kc (lane bits 0..4)
#pragma unroll
        for (int off = 1; off <= 16; off <<= 1)
#pragma unroll
            for (int jj = 0; jj < 8; ++jj) {
                acc0[jj] += __shfl_xor(acc0[jj], off, 64);
                acc1[jj] += __shfl_xor(acc1[jj], off, 64);
            }
        if (kc == 0)
#pragma unroll
            for (int jj = 0; jj < 8; ++jj) {
                G_lds[0][jq * 8 + jj] = acc0[jj];
                G_lds[1][jq * 8 + jj] = acc1[jj];
            }
        __syncthreads();                          // C

        // phase 5: LSTM update + policy partials (wave 0: threads 0..63)
        if (tid < 64) {
            float pv = s_prev[sb_b];
            float gi = G_lds[sb_b][ 0 + sb_f] + biasr[0] + pv * wpbr[0];
            float gf = G_lds[sb_b][32 + sb_f] + biasr[1] + pv * wpbr[1];
            float gg = G_lds[sb_b][64 + sb_f] + biasr[2] + pv * wpbr[2];
            float go = G_lds[sb_b][96 + sb_f] + biasr[3] + pv * wpbr[3];
            float ig = 1.f / (1.f + expf(-gi));
            float fg = 1.f / (1.f + expf(-gf));
            float gt = tanhf(gg);
            float og = 1.f / (1.f + expf(-go));
            c_reg = fg * c_reg + ig * gt;
            float h = og * tanhf(c_reg);
            hx[(((size_t)cur * NGRP + p) * NB + sb_b) * FEAT + s * FPS + sb_f] = h;
            float p0 = h * wp0, p1 = h * wp1;
#pragma unroll
            for (int off2 = 16; off2 > 0; off2 >>= 1) {   // within 32-lane half
                p0 += __shfl_xor(p0, off2, 64);
                p1 += __shfl_xor(p1, off2, 64);
            }
            if (sb_f == 0) {
                float* pp = &pol[(((size_t)cur * NGRP + p) * NSLICE + s) * 4 + sb_b * 2];
                pp[0] = p0; pp[1] = p1;
            }
            __threadfence();                      // release (writer wave only)
        }
        __syncthreads();                          // D
        if (tid == 0)
            __hip_atomic_store(&flags[s * 32], (unsigned)(t + 1),
                               __ATOMIC_RELEASE, __HIP_MEMORY_SCOPE_AGENT);

        // phase 6: roll x prefetch into the live window
        if (pfx) {
#pragma unroll
            for (int q = 0; q < 4; ++q) {
                hv0[q*4+0]=xnA[q].x; hv0[q*4+1]=xnA[q].y; hv0[q*4+2]=xnA[q].z; hv0[q*4+3]=xnA[q].w;
                hv1[q*4+0]=xnB[q].x; hv1[q*4+1]=xnB[q].y; hv1[q*4+2]=xnB[q].z; hv1[q*4+3]=xnB[q].w;
            }
        }
    }
}

extern "C" void kernel_launch(void* const* d_in, const int* in_sizes, int n_in,
                              void* d_out, int out_size, void* d_ws, size_t ws_size,
                              hipStream_t stream)
{
    const float* x    = (const float*)d_in[0];
    // d_in[1] = label (unused by the reference forward)
    const float* W_ih = (const float*)d_in[2];
    const float* W_hh = (const float*)d_in[3];
    const float* b_ih = (const float*)d_in[4];
    const float* b_hh = (const float*)d_in[5];
    const float* Wp   = (const float*)d_in[6];
    const float* bp   = (const float*)d_in[7];

    float* ws      = (float*)d_ws;
    float* out_b   = (float*)d_out;
    float* out_sel = out_b + (size_t)64 * SEQ;

    // zero sync region (flags/hx/pol) every call -> deterministic, capture-safe
    hipMemsetAsync(d_ws, 0, SYNC_FLOATS * sizeof(float), stream);

    hipLaunchKernelGGL(seq_kernel, dim3(NSLICE * NGRP), dim3(512), 0, stream,
                       x, W_ih, W_hh, b_ih, b_hh, Wp, bp, ws, out_b, out_sel);
}

// Round 5
// 14893.777 us; speedup vs baseline: 5.8017x; 5.8017x over previous
//
#include <hip/hip_runtime.h>
#include <cstdint>
#include <cmath>

#define FEAT 256
#define GATES 1024
#define BS 64
#define SEQ 2048
#define NEG_BIG -10000.0f
#define MIN_SEG 3.0f

#define KK_REG 12                 // k-rows per chunk held in VGPRs
#define KK_LDS 6                  // k-rows per chunk held in LDS
#define KK_STA (KK_REG + KK_LDS)  // 18; remaining 46 streamed from L2

// ---- mode0 ws layout (floats): chunked-XP path ----
#define M0_WPB  262144            // [1024] W_ih[:,0] (prev-boundary column)
#define M0_BIAS 263168            // [1024] b_ih + b_hh
#define M0_H    264192            // [64][256] h state across chunk launches
#define M0_C    280576            // [64][256] c state
#define M0_PF   296960            // [64][2] prev,flag
#define M0_XP   297984            // [T][64][1024] x-projection window (+bias)
// ---- mode1 ws layout (floats): fused fallback (proven to fit: 2.105 MB) ----
#define M1_WIT  262144            // [256][1024] W_ih[:,1:]^T
#define M1_WPB  524288
#define M1_BIAS 525312
#define M1_TOT  526336

template<int MODE>
__global__ __launch_bounds__(1024) void prep_kernel(
    const float* __restrict__ W_ih, const float* __restrict__ W_hh,
    const float* __restrict__ b_ih, const float* __restrict__ b_hh,
    float* __restrict__ ws)
{
    const int k = blockIdx.x;    // 0..255
    const int j = threadIdx.x;   // 0..1023
    ws[k * GATES + j] = W_hh[(size_t)j * FEAT + k];          // WT[k][j]
    if (MODE == 1)
        ws[M1_WIT + k * GATES + j] = W_ih[(size_t)j * (FEAT + 1) + 1 + k];
    if (k == 0) {
        const int WPB = MODE ? M1_WPB : M0_WPB;
        const int BIA = MODE ? M1_BIAS : M0_BIAS;
        ws[WPB + j] = W_ih[(size_t)j * (FEAT + 1)];
        ws[BIA + j] = b_ih[j] + b_hh[j];
    }
    if (MODE == 0 && k == 1) {
#pragma unroll
        for (int i = 0; i < 16; ++i) {
            ws[M0_H + i * 1024 + j] = 0.f;
            ws[M0_C + i * 1024 + j] = 0.f;
        }
        if (j < 128) ws[M0_PF + j] = 0.f;
    }
}

// XP[trow][b][j] = sum_k x[b][t0+trow][k] * W_ih[j][k+1] + bias[j]
__global__ __launch_bounds__(256) void xproj_gemm(
    const float* __restrict__ x, const float* __restrict__ W_ih,
    float* __restrict__ ws, int t0)
{
    const int trow = blockIdx.y;
    const int t  = t0 + trow;
    const int j0 = blockIdx.x * 64;
    const int tid = threadIdx.x;
    const int ty = tid >> 4, tx = tid & 15;
    const float* bias = ws + M0_BIAS;
    float* XP = ws + M0_XP;
    __shared__ __align__(16) float As[64][65];   // [b][k]
    __shared__ __align__(16) float Bs[64][65];   // [k][j]
    float acc[4][4] = {};
    for (int k0 = 0; k0 < FEAT; k0 += 64) {
#pragma unroll
        for (int i = 0; i < 16; ++i) {
            int idx = i * 256 + tid;
            int rr = idx >> 6, cc = idx & 63;
            As[rr][cc] = x[((size_t)rr * SEQ + t) * FEAT + k0 + cc];
        }
#pragma unroll
        for (int i = 0; i < 16; ++i) {
            int idx = i * 256 + tid;
            int jj = idx >> 6, kk = idx & 63;
            Bs[kk][jj] = W_ih[(size_t)(j0 + jj) * (FEAT + 1) + 1 + k0 + kk];
        }
        __syncthreads();
#pragma unroll
        for (int kk = 0; kk < 64; ++kk) {
            float a[4], bv[4];
#pragma unroll
            for (int r = 0; r < 4; ++r) a[r] = As[ty * 4 + r][kk];
#pragma unroll
            for (int c = 0; c < 4; ++c) bv[c] = Bs[kk][tx * 4 + c];
#pragma unroll
            for (int r = 0; r < 4; ++r)
#pragma unroll
                for (int c = 0; c < 4; ++c)
                    acc[r][c] = fmaf(a[r], bv[c], acc[r][c]);
        }
        __syncthreads();
    }
#pragma unroll
    for (int r = 0; r < 4; ++r) {
        int bb = ty * 4 + r;
        size_t base = ((size_t)trow * BS + bb) * GATES + j0 + tx * 4;
        float4 v;
        v.x = acc[r][0] + bias[j0 + tx * 4 + 0];
        v.y = acc[r][1] + bias[j0 + tx * 4 + 1];
        v.z = acc[r][2] + bias[j0 + tx * 4 + 2];
        v.w = acc[r][3] + bias[j0 + tx * 4 + 3];
        *(float4*)&XP[base] = v;
    }
}

#define FMA4(acc, hb, wv) \
    acc.x = fmaf(hb, wv.x, acc.x); acc.y = fmaf(hb, wv.y, acc.y); \
    acc.z = fmaf(hb, wv.z, acc.z); acc.w = fmaf(hb, wv.w, acc.w);

// One block per batch element. 1024 threads = 4 k-chunks x 256 gate-quads.
// No cross-block communication of any kind.
template<int MODE>
__global__ __launch_bounds__(1024) void consumer(
    const float* __restrict__ x, float* __restrict__ ws,
    const float* __restrict__ Wp, const float* __restrict__ bp,
    float* __restrict__ out_b, float* __restrict__ out_sel,
    int t0, int Tlen)
{
    const int b   = blockIdx.x;
    const int tid = threadIdx.x;
    const int ch  = tid >> 8;          // k-chunk 0..3 (k in [ch*64, ch*64+64))
    const int j4  = (tid & 255) * 4;   // gate quad
    const int f   = tid & 255;         // feature (phase-2 role)
    const int kbase = ch * 64;

    const float* WT   = ws;                                  // [256][1024]
    const float* WIT  = ws + M1_WIT;                         // mode1 only
    const float* WPB  = ws + (MODE ? M1_WPB : M0_WPB);
    const float* BIAS = ws + (MODE ? M1_BIAS : M0_BIAS);
    float* H  = ws + M0_H;
    float* C  = ws + M0_C;
    float* PF = ws + M0_PF;
    const float* XP = ws + M0_XP;                            // mode0 window

    __shared__ __align__(16) float wlds[4 * KK_LDS * 1024];  // 96 KB
    __shared__ __align__(16) float part[4][GATES];           // 16 KB
    __shared__ __align__(16) float h_lds[FEAT];
    __shared__ __align__(16) float xp_lds[2][GATES];         // mode1 uses [.][0..255]
    __shared__ float red[8];
    __shared__ float s_pv[2];                                // prev, flag

    // ---- stationary weights: registers ----
    float4 wreg[KK_REG];
#pragma unroll
    for (int kk = 0; kk < KK_REG; ++kk)
        wreg[kk] = *(const float4*)&WT[(size_t)(kbase + kk) * GATES + j4];
    // ---- stationary weights: LDS (rows KK_REG..KK_STA-1 of each chunk) ----
#pragma unroll
    for (int i = 0; i < 4 * KK_LDS; ++i) {
        int ch2 = i / KK_LDS, kkl = i % KK_LDS;
        wlds[i * 1024 + tid] = WT[(size_t)(ch2 * 64 + KK_REG + kkl) * GATES + tid];
    }

    // ---- per-feature params (phase-2 threads) ----
    float biasr[4] = {}, wpbr[4] = {};
    float wp0 = 0.f, wp1 = 0.f, c_reg = 0.f;
    if (tid < FEAT) {
#pragma unroll
        for (int g = 0; g < 4; ++g) {
            wpbr[g] = WPB[g * FEAT + f];
            if (MODE == 1) biasr[g] = BIAS[g * FEAT + f];
        }
        wp0 = Wp[f]; wp1 = Wp[FEAT + f];
        c_reg = (MODE == 0) ? C[b * FEAT + f] : 0.f;
        h_lds[f] = (MODE == 0) ? H[b * FEAT + f] : 0.f;
    }
    const float bp0 = bp[0], bp1 = bp[1];
    // preload step-0 xp / x
    if (MODE == 0) {
        xp_lds[0][tid] = XP[(size_t)b * GATES + tid];        // window row 0
    } else if (tid < FEAT) {
        xp_lds[0][tid] = x[((size_t)b * SEQ + t0) * FEAT + tid];
    }
    if (tid == 0) {
        s_pv[0] = (MODE == 0) ? PF[b * 2 + 0] : 0.f;
        s_pv[1] = (MODE == 0) ? PF[b * 2 + 1] : 0.f;
    }
    __syncthreads();

    float fl_r = 0.f;                  // tid0's private copy of flag
    if (tid == 0) fl_r = s_pv[1];

    for (int tl = 0; tl < Tlen; ++tl) {
        const int t   = t0 + tl;
        const int buf = tl & 1;

        // prefetch next step's xp (mode0, 1 float/thread) or x (mode1)
        float xpf = 0.f;
        bool haspf;
        if (MODE == 0) {
            haspf = (tl + 1 < Tlen);
            if (haspf) xpf = XP[((size_t)(tl + 1) * BS + b) * GATES + tid];
        } else {
            haspf = (t + 1 < SEQ) && (tid < FEAT);
            if (haspf) xpf = x[((size_t)b * SEQ + (t + 1)) * FEAT + tid];
        }

        // ---- phase 1: gate matvec (all 16 waves) ----
        float4 acc = make_float4(0.f, 0.f, 0.f, 0.f);
#pragma unroll
        for (int kk = 0; kk < KK_REG; ++kk) {
            float hb = h_lds[kbase + kk];
            FMA4(acc, hb, wreg[kk]);
        }
#pragma unroll
        for (int kk = 0; kk < KK_LDS; ++kk) {
            float hb = h_lds[kbase + KK_REG + kk];
            float4 wv = *(const float4*)&wlds[(ch * KK_LDS + kk) * 1024 + j4];
            FMA4(acc, hb, wv);
        }
#pragma unroll 4
        for (int kk = KK_STA; kk < 64; ++kk) {
            float hb = h_lds[kbase + kk];
            float4 wv = *(const float4*)&WT[(size_t)(kbase + kk) * GATES + j4];
            FMA4(acc, hb, wv);
        }
        if (MODE == 1) {
#pragma unroll 4
            for (int kk = 0; kk < 64; ++kk) {
                float xb = xp_lds[buf][kbase + kk];
                float4 wv = *(const float4*)&WIT[(size_t)(kbase + kk) * GATES + j4];
                FMA4(acc, xb, wv);
            }
        }
        *(float4*)&part[ch][j4] = acc;
        __syncthreads();                                     // A

        // route prefetch to LDS for next step
        if (haspf) xp_lds[buf ^ 1][tid] = xpf;

        // ---- phase 2: gate combine + LSTM + policy (threads 0..255) ----
        if (tid < FEAT) {
            const float pvv = s_pv[0];
            float gv[4];
#pragma unroll
            for (int g = 0; g < 4; ++g) {
                const int jj = g * FEAT + f;
                gv[g] = part[0][jj] + part[1][jj] + part[2][jj] + part[3][jj]
                      + (MODE == 0 ? xp_lds[buf][jj] : biasr[g])
                      + pvv * wpbr[g];
            }
            float ig = 1.f / (1.f + expf(-gv[0]));
            float fg = 1.f / (1.f + expf(-gv[1]));
            float gt = tanhf(gv[2]);
            float og = 1.f / (1.f + expf(-gv[3]));
            c_reg = fg * c_reg + ig * gt;
            float h = og * tanhf(c_reg);
            h_lds[f] = h;
            if (MODE == 0 && tl == Tlen - 1) {
                H[b * FEAT + f] = h;
                C[b * FEAT + f] = c_reg;
            }
            float p0 = h * wp0, p1 = h * wp1;
#pragma unroll
            for (int off = 32; off > 0; off >>= 1) {
                p0 += __shfl_xor(p0, off, 64);
                p1 += __shfl_xor(p1, off, 64);
            }
            if ((tid & 63) == 0) {
                red[tid >> 6] = p0;
                red[4 + (tid >> 6)] = p1;
            }
        }
        __syncthreads();                                     // B

        // ---- phase 3: decision (tid 0). s_pv consumers are behind barrier A
        // of step t+1, so no third barrier is needed (r1-proven pattern).
        if (tid == 0) {
            float l0 = red[0] + red[1] + red[2] + red[3] + bp0;
            float l1 = red[4] + red[5] + red[6] + red[7] + bp1;
            if (fl_r > 0.0f) l1 += NEG_BIG;
            int samp = (l1 > l0) ? 1 : 0;
            float a0 = l0 * 0.5f, a1 = l1 * 0.5f;   // logits / TAU, TAU = 2
            float m = fmaxf(a0, a1);
            float lse = m + logf(expf(a0 - m) + expf(a1 - m));
            out_b[(size_t)b * SEQ + t]   = (float)samp;
            out_sel[(size_t)b * SEQ + t] = (samp ? a1 : a0) - lse;
            fl_r = (fl_r > 0.0f) ? (fl_r - 1.0f) : fl_r;
            if (samp) fl_r = MIN_SEG;
            s_pv[0] = (float)samp;
            if (MODE == 0 && tl == Tlen - 1) {
                PF[b * 2 + 0] = (float)samp;
                PF[b * 2 + 1] = fl_r;
            }
        }
    }
}

extern "C" void kernel_launch(void* const* d_in, const int* in_sizes, int n_in,
                              void* d_out, int out_size, void* d_ws, size_t ws_size,
                              hipStream_t stream)
{
    const float* x    = (const float*)d_in[0];
    // d_in[1] = label (unused by the reference forward)
    const float* W_ih = (const float*)d_in[2];
    const float* W_hh = (const float*)d_in[3];
    const float* b_ih = (const float*)d_in[4];
    const float* b_hh = (const float*)d_in[5];
    const float* Wp   = (const float*)d_in[6];
    const float* bp   = (const float*)d_in[7];

    float* ws      = (float*)d_ws;
    float* out_b   = (float*)d_out;
    float* out_sel = out_b + (size_t)BS * SEQ;

    // pick largest chunk length whose XP window fits in ws
    int T = 0;
    for (int cand = 128; cand >= 8; cand >>= 1) {
        size_t need = ((size_t)M0_XP + (size_t)cand * BS * GATES) * sizeof(float);
        if (ws_size >= need) { T = cand; break; }
    }

    if (T > 0) {
        hipLaunchKernelGGL((prep_kernel<0>), dim3(FEAT), dim3(GATES), 0, stream,
                           W_ih, W_hh, b_ih, b_hh, ws);
        const int nch = SEQ / T;
        for (int c = 0; c < nch; ++c) {
            hipLaunchKernelGGL(xproj_gemm, dim3(GATES / 64, T), dim3(256), 0, stream,
                               x, W_ih, ws, c * T);
            hipLaunchKernelGGL((consumer<0>), dim3(BS), dim3(1024), 0, stream,
                               x, ws, Wp, bp, out_b, out_sel, c * T, T);
        }
    } else {
        // fused fallback (ws proven >= 2.105 MB by round-1's mode-1 run)
        hipLaunchKernelGGL((prep_kernel<1>), dim3(FEAT), dim3(GATES), 0, stream,
                           W_ih, W_hh, b_ih, b_hh, ws);
        hipLaunchKernelGGL((consumer<1>), dim3(BS), dim3(1024), 0, stream,
                           x, ws, Wp, bp, out_b, out_sel, 0, SEQ);
    }
}

// Round 6
// 13852.505 us; speedup vs baseline: 6.2378x; 1.0752x over previous
//
#include <hip/hip_runtime.h>
#include <cstdint>
#include <cmath>

#define FEAT 256
#define GATES 1024
#define BS 64
#define SEQ 2048
#define NEG_BIG -10000.0f
#define MIN_SEG 3.0f

#define KK_REG 24                 // k-rows per chunk in VGPRs (96 regs)
#define KK_LDS 8                  // k-rows per chunk in LDS (128 KB)
#define KK_STA (KK_REG + KK_LDS)  // 32; remaining 32 streamed from L2
#define NGEMM 192                 // gemm-role blocks in fused kernel

// ---- mode0 ws layout (floats) ----
#define M0_WPB  262144            // [1024] W_ih[:,0]
#define M0_BIAS 263168            // [1024] b_ih + b_hh
#define M0_H    264192            // [64][256]
#define M0_C    280576            // [64][256]
#define M0_PF   296960            // [64][2] prev,flag
#define M0_XP   297984            // two [T][64][1024] windows follow
// ---- mode1 fallback layout (proven to fit: 2.105 MB) ----
#define M1_WIT  262144
#define M1_WPB  524288
#define M1_BIAS 525312

template<int MODE>
__global__ __launch_bounds__(1024) void prep_kernel(
    const float* __restrict__ W_ih, const float* __restrict__ W_hh,
    const float* __restrict__ b_ih, const float* __restrict__ b_hh,
    float* __restrict__ ws)
{
    const int k = blockIdx.x;    // 0..255
    const int j = threadIdx.x;   // 0..1023
    ws[k * GATES + j] = W_hh[(size_t)j * FEAT + k];          // WT[k][j]
    if (MODE == 1)
        ws[M1_WIT + k * GATES + j] = W_ih[(size_t)j * (FEAT + 1) + 1 + k];
    if (k == 0) {
        const int WPB = MODE ? M1_WPB : M0_WPB;
        const int BIA = MODE ? M1_BIAS : M0_BIAS;
        ws[WPB + j] = W_ih[(size_t)j * (FEAT + 1)];
        ws[BIA + j] = b_ih[j] + b_hh[j];
    }
    if (MODE == 0 && k == 1) {
#pragma unroll
        for (int i = 0; i < 16; ++i) {
            ws[M0_H + i * 1024 + j] = 0.f;
            ws[M0_C + i * 1024 + j] = 0.f;
        }
        if (j < 128) ws[M0_PF + j] = 0.f;
    }
}

// Prologue GEMM for window 0: XP[trow][b][j] = x(t0+trow) @ W_ih[:,1:]^T + bias
__global__ __launch_bounds__(256) void xproj_gemm(
    const float* __restrict__ x, const float* __restrict__ W_ih,
    float* __restrict__ ws, int t0, int xpoff)
{
    const int trow = blockIdx.y;
    const int t  = t0 + trow;
    const int j0 = blockIdx.x * 64;
    const int tid = threadIdx.x;
    const int ty = tid >> 4, tx = tid & 15;
    const float* bias = ws + M0_BIAS;
    float* XP = ws + xpoff;
    __shared__ __align__(16) float As[64][65];
    __shared__ __align__(16) float Bs[64][65];
    float acc[4][4] = {};
    for (int k0 = 0; k0 < FEAT; k0 += 64) {
#pragma unroll
        for (int i = 0; i < 16; ++i) {
            int idx = i * 256 + tid;
            int rr = idx >> 6, cc = idx & 63;
            As[rr][cc] = x[((size_t)rr * SEQ + t) * FEAT + k0 + cc];
        }
#pragma unroll
        for (int i = 0; i < 16; ++i) {
            int idx = i * 256 + tid;
            int jj = idx >> 6, kk = idx & 63;
            Bs[kk][jj] = W_ih[(size_t)(j0 + jj) * (FEAT + 1) + 1 + k0 + kk];
        }
        __syncthreads();
#pragma unroll
        for (int kk = 0; kk < 64; ++kk) {
            float a[4], bv[4];
#pragma unroll
            for (int r = 0; r < 4; ++r) a[r] = As[ty * 4 + r][kk];
#pragma unroll
            for (int c = 0; c < 4; ++c) bv[c] = Bs[kk][tx * 4 + c];
#pragma unroll
            for (int r = 0; r < 4; ++r)
#pragma unroll
                for (int c = 0; c < 4; ++c)
                    acc[r][c] = fmaf(a[r], bv[c], acc[r][c]);
        }
        __syncthreads();
    }
#pragma unroll
    for (int r = 0; r < 4; ++r) {
        int bb = ty * 4 + r;
        size_t base = ((size_t)trow * BS + bb) * GATES + j0 + tx * 4;
        float4 v;
        v.x = acc[r][0] + bias[j0 + tx * 4 + 0];
        v.y = acc[r][1] + bias[j0 + tx * 4 + 1];
        v.z = acc[r][2] + bias[j0 + tx * 4 + 2];
        v.w = acc[r][3] + bias[j0 + tx * 4 + 3];
        *(float4*)&XP[base] = v;
    }
}

#define FMA4(acc, hb, wv) \
    acc.x = fmaf(hb, wv.x, acc.x); acc.y = fmaf(hb, wv.y, acc.y); \
    acc.z = fmaf(hb, wv.z, acc.z); acc.w = fmaf(hb, wv.w, acc.w);

// Heterogeneous kernel: blocks 0..63 = recurrence on window xp_cur;
// blocks 64..255 = GEMM producing next chunk's XP into xp_nxt (if >= 0).
// The two roles touch disjoint ws regions; kernel boundary is the only sync.
__global__ __launch_bounds__(1024, 1) void fused_kernel(
    const float* __restrict__ x, const float* __restrict__ W_ih,
    float* __restrict__ ws,
    const float* __restrict__ Wp, const float* __restrict__ bp,
    float* __restrict__ out_b, float* __restrict__ out_sel,
    int t0, int Tlen, int xp_cur, int xp_nxt)
{
    __shared__ __align__(16) float smem[39178];   // 156.7 KB, overlaid per role
    const int tid = threadIdx.x;

    if (blockIdx.x >= BS) {
        // ================= GEMM role =================
        if (xp_nxt < 0) return;
        float* As = smem;            // [64][65]
        float* Bs = smem + 4160;     // [64][260]  (260: float4-aligned rows)
        const float* bias = ws + M0_BIAS;
        float* XPn = ws + xp_nxt;
        const int ty = tid >> 6, tx = tid & 63;   // ty uniform per wave
        const int jobs = Tlen * 4;                // (trow, j-quarter)
        for (int job = blockIdx.x - BS; job < jobs; job += NGEMM) {
            const int trow = job >> 2;
            const int j0 = (job & 3) * 256;
            const int t = t0 + Tlen + trow;
            float acc[4][4] = {};
            for (int k0 = 0; k0 < FEAT; k0 += 64) {
                __syncthreads();                   // WAR on LDS reuse
#pragma unroll
                for (int i = 0; i < 4; ++i) {
                    int idx = i * 1024 + tid, rr = idx >> 6, cc = idx & 63;
                    As[rr * 65 + cc] = x[((size_t)rr * SEQ + t) * FEAT + k0 + cc];
                }
#pragma unroll
                for (int i = 0; i < 16; ++i) {
                    int idx = i * 1024 + tid, jj = idx >> 6, kk = idx & 63;
                    Bs[kk * 260 + jj] = W_ih[(size_t)(j0 + jj) * (FEAT + 1) + 1 + k0 + kk];
                }
                __syncthreads();
#pragma unroll
                for (int kk = 0; kk < 64; ++kk) {
                    float4 bv = *(const float4*)&Bs[kk * 260 + tx * 4];
                    float a[4];
#pragma unroll
                    for (int r = 0; r < 4; ++r) a[r] = As[(ty * 4 + r) * 65 + kk];
#pragma unroll
                    for (int r = 0; r < 4; ++r) {
                        acc[r][0] = fmaf(a[r], bv.x, acc[r][0]);
                        acc[r][1] = fmaf(a[r], bv.y, acc[r][1]);
                        acc[r][2] = fmaf(a[r], bv.z, acc[r][2]);
                        acc[r][3] = fmaf(a[r], bv.w, acc[r][3]);
                    }
                }
            }
#pragma unroll
            for (int r = 0; r < 4; ++r) {
                int bb = ty * 4 + r;
                size_t base = ((size_t)trow * BS + bb) * GATES + j0 + tx * 4;
                float4 v;
                v.x = acc[r][0] + bias[j0 + tx * 4 + 0];
                v.y = acc[r][1] + bias[j0 + tx * 4 + 1];
                v.z = acc[r][2] + bias[j0 + tx * 4 + 2];
                v.w = acc[r][3] + bias[j0 + tx * 4 + 3];
                *(float4*)&XPn[base] = v;
            }
        }
        return;
    }

    // ================= consumer role =================
    const int b   = blockIdx.x;
    const int ch  = tid >> 8;          // k-chunk 0..3
    const int j4  = (tid & 255) * 4;   // gate quad
    const int f   = tid & 255;         // feature (phase-2 role)
    const int kbase = ch * 64;

    const float* WT   = ws;
    const float* WPB  = ws + M0_WPB;
    float* H  = ws + M0_H;
    float* C  = ws + M0_C;
    float* PF = ws + M0_PF;
    const float* XPc = ws + xp_cur;

    float* wlds   = smem;              // [4*KK_LDS][1024]  128 KB
    float* part   = smem + 32768;      // [4][1024]
    float* h_lds  = smem + 36864;      // [256]
    float* xp_lds = smem + 37120;      // [2][1024]
    float* red    = smem + 39168;      // [8]
    float* s_pv   = smem + 39176;      // [2] prev, flag

    // stationary weights: registers (24 rows/chunk x float4 = 96 VGPR)
    float4 wreg[KK_REG];
#pragma unroll
    for (int kk = 0; kk < KK_REG; ++kk)
        wreg[kk] = *(const float4*)&WT[(size_t)(kbase + kk) * GATES + j4];
    // stationary weights: LDS (rows KK_REG..KK_STA-1 of each chunk)
#pragma unroll
    for (int i = 0; i < 4 * KK_LDS; ++i) {
        int ch2 = i / KK_LDS, kkl = i % KK_LDS;
        wlds[i * 1024 + tid] = WT[(size_t)(ch2 * 64 + KK_REG + kkl) * GATES + tid];
    }

    float wpbr[4] = {};
    float wp0 = 0.f, wp1 = 0.f, c_reg = 0.f;
    if (tid < FEAT) {
#pragma unroll
        for (int g = 0; g < 4; ++g) wpbr[g] = WPB[g * FEAT + f];
        wp0 = Wp[f]; wp1 = Wp[FEAT + f];
        c_reg = C[b * FEAT + f];
        h_lds[f] = H[b * FEAT + f];
    }
    const float bp0 = bp[0], bp1 = bp[1];
    xp_lds[tid] = XPc[(size_t)b * GATES + tid];       // window row 0
    if (tid == 0) { s_pv[0] = PF[b * 2 + 0]; s_pv[1] = PF[b * 2 + 1]; }
    __syncthreads();

    float fl_r = 0.f;
    if (tid == 0) fl_r = s_pv[1];

    for (int tl = 0; tl < Tlen; ++tl) {
        const int t   = t0 + tl;
        const int buf = tl & 1;

        // prefetch next step's xp row (1 float/thread)
        float xpf = 0.f;
        const bool haspf = (tl + 1 < Tlen);
        if (haspf) xpf = XPc[((size_t)(tl + 1) * BS + b) * GATES + tid];

        // ---- phase 1: gate matvec (all 16 waves) ----
        float4 acc = make_float4(0.f, 0.f, 0.f, 0.f);
#pragma unroll
        for (int kk = 0; kk < KK_REG; ++kk) {
            float hb = h_lds[kbase + kk];
            FMA4(acc, hb, wreg[kk]);
        }
#pragma unroll
        for (int kk = 0; kk < KK_LDS; ++kk) {
            float hb = h_lds[kbase + KK_REG + kk];
            float4 wv = *(const float4*)&wlds[(ch * KK_LDS + kk) * 1024 + j4];
            FMA4(acc, hb, wv);
        }
#pragma unroll 4
        for (int kk = KK_STA; kk < 64; ++kk) {
            float hb = h_lds[kbase + kk];
            float4 wv = *(const float4*)&WT[(size_t)(kbase + kk) * GATES + j4];
            FMA4(acc, hb, wv);
        }
        *(float4*)&part[ch * 1024 + j4] = acc;
        __syncthreads();                                     // A

        if (haspf) xp_lds[(buf ^ 1) * 1024 + tid] = xpf;

        // ---- phase 2: gate combine + LSTM + policy (threads 0..255) ----
        if (tid < FEAT) {
            const float pvv = s_pv[0];
            float gv[4];
#pragma unroll
            for (int g = 0; g < 4; ++g) {
                const int jj = g * FEAT + f;
                gv[g] = part[jj] + part[1024 + jj] + part[2048 + jj] + part[3072 + jj]
                      + xp_lds[buf * 1024 + jj] + pvv * wpbr[g];
            }
            float ig = 1.f / (1.f + expf(-gv[0]));
            float fg = 1.f / (1.f + expf(-gv[1]));
            float gt = tanhf(gv[2]);
            float og = 1.f / (1.f + expf(-gv[3]));
            c_reg = fg * c_reg + ig * gt;
            float h = og * tanhf(c_reg);
            h_lds[f] = h;
            if (tl == Tlen - 1) {
                H[b * FEAT + f] = h;
                C[b * FEAT + f] = c_reg;
            }
            float p0 = h * wp0, p1 = h * wp1;
#pragma unroll
            for (int off = 32; off > 0; off >>= 1) {
                p0 += __shfl_xor(p0, off, 64);
                p1 += __shfl_xor(p1, off, 64);
            }
            if ((tid & 63) == 0) {
                red[tid >> 6] = p0;
                red[4 + (tid >> 6)] = p1;
            }
        }
        __syncthreads();                                     // B

        // ---- phase 3: decision (tid 0); consumers of s_pv are behind
        // barrier A of step t+1 (r1/r5-proven pattern).
        if (tid == 0) {
            float l0 = red[0] + red[1] + red[2] + red[3] + bp0;
            float l1 = red[4] + red[5] + red[6] + red[7] + bp1;
            if (fl_r > 0.0f) l1 += NEG_BIG;
            int samp = (l1 > l0) ? 1 : 0;
            float a0 = l0 * 0.5f, a1 = l1 * 0.5f;   // logits / TAU, TAU = 2
            float m = fmaxf(a0, a1);
            float lse = m + logf(expf(a0 - m) + expf(a1 - m));
            out_b[(size_t)b * SEQ + t]   = (float)samp;
            out_sel[(size_t)b * SEQ + t] = (samp ? a1 : a0) - lse;
            fl_r = (fl_r > 0.0f) ? (fl_r - 1.0f) : fl_r;
            if (samp) fl_r = MIN_SEG;
            s_pv[0] = (float)samp;
            if (tl == Tlen - 1) {
                PF[b * 2 + 0] = (float)samp;
                PF[b * 2 + 1] = fl_r;
            }
        }
    }
}

// ---- mode1 fallback (tiny ws): fused streaming consumer, r5-proven ----
__global__ __launch_bounds__(1024) void consumer1(
    const float* __restrict__ x, float* __restrict__ ws,
    const float* __restrict__ Wp, const float* __restrict__ bp,
    float* __restrict__ out_b, float* __restrict__ out_sel)
{
    const int b   = blockIdx.x;
    const int tid = threadIdx.x;
    const int ch  = tid >> 8;
    const int j4  = (tid & 255) * 4;
    const int f   = tid & 255;
    const int kbase = ch * 64;

    const float* WT   = ws;
    const float* WIT  = ws + M1_WIT;
    const float* WPB  = ws + M1_WPB;
    const float* BIAS = ws + M1_BIAS;

    __shared__ __align__(16) float part[4][GATES];
    __shared__ __align__(16) float h_lds[FEAT];
    __shared__ __align__(16) float x_lds[2][FEAT];
    __shared__ float red[8];
    __shared__ float s_pv[2];

    float biasr[4] = {}, wpbr[4] = {};
    float wp0 = 0.f, wp1 = 0.f, c_reg = 0.f;
    if (tid < FEAT) {
#pragma unroll
        for (int g = 0; g < 4; ++g) {
            wpbr[g]  = WPB[g * FEAT + f];
            biasr[g] = BIAS[g * FEAT + f];
        }
        wp0 = Wp[f]; wp1 = Wp[FEAT + f];
        h_lds[f] = 0.f;
        x_lds[0][f] = x[(size_t)b * SEQ * FEAT + f];
    }
    const float bp0 = bp[0], bp1 = bp[1];
    if (tid == 0) { s_pv[0] = 0.f; s_pv[1] = 0.f; }
    __syncthreads();

    float fl_r = 0.f;
    for (int t = 0; t < SEQ; ++t) {
        const int buf = t & 1;
        float xpf = 0.f;
        const bool haspf = (t + 1 < SEQ) && (tid < FEAT);
        if (haspf) xpf = x[((size_t)b * SEQ + (t + 1)) * FEAT + f];

        float4 acc = make_float4(0.f, 0.f, 0.f, 0.f);
#pragma unroll 4
        for (int kk = 0; kk < 64; ++kk) {
            float hb = h_lds[kbase + kk];
            float4 wv = *(const float4*)&WT[(size_t)(kbase + kk) * GATES + j4];
            FMA4(acc, hb, wv);
            float xb = x_lds[buf][kbase + kk];
            float4 wi = *(const float4*)&WIT[(size_t)(kbase + kk) * GATES + j4];
            FMA4(acc, xb, wi);
        }
        *(float4*)&part[ch][j4] = acc;
        __syncthreads();
        if (haspf) x_lds[buf ^ 1][f] = xpf;

        if (tid < FEAT) {
            const float pvv = s_pv[0];
            float gv[4];
#pragma unroll
            for (int g = 0; g < 4; ++g) {
                const int jj = g * FEAT + f;
                gv[g] = part[0][jj] + part[1][jj] + part[2][jj] + part[3][jj]
                      + biasr[g] + pvv * wpbr[g];
            }
            float ig = 1.f / (1.f + expf(-gv[0]));
            float fg = 1.f / (1.f + expf(-gv[1]));
            float gt = tanhf(gv[2]);
            float og = 1.f / (1.f + expf(-gv[3]));
            c_reg = fg * c_reg + ig * gt;
            float h = og * tanhf(c_reg);
            h_lds[f] = h;
            float p0 = h * wp0, p1 = h * wp1;
#pragma unroll
            for (int off = 32; off > 0; off >>= 1) {
                p0 += __shfl_xor(p0, off, 64);
                p1 += __shfl_xor(p1, off, 64);
            }
            if ((tid & 63) == 0) { red[tid >> 6] = p0; red[4 + (tid >> 6)] = p1; }
        }
        __syncthreads();

        if (tid == 0) {
            float l0 = red[0] + red[1] + red[2] + red[3] + bp0;
            float l1 = red[4] + red[5] + red[6] + red[7] + bp1;
            if (fl_r > 0.0f) l1 += NEG_BIG;
            int samp = (l1 > l0) ? 1 : 0;
            float a0 = l0 * 0.5f, a1 = l1 * 0.5f;
            float m = fmaxf(a0, a1);
            float lse = m + logf(expf(a0 - m) + expf(a1 - m));
            out_b[(size_t)b * SEQ + t]   = (float)samp;
            out_sel[(size_t)b * SEQ + t] = (samp ? a1 : a0) - lse;
            fl_r = (fl_r > 0.0f) ? (fl_r - 1.0f) : fl_r;
            if (samp) fl_r = MIN_SEG;
            s_pv[0] = (float)samp;
        }
    }
}

extern "C" void kernel_launch(void* const* d_in, const int* in_sizes, int n_in,
                              void* d_out, int out_size, void* d_ws, size_t ws_size,
                              hipStream_t stream)
{
    const float* x    = (const float*)d_in[0];
    // d_in[1] = label (unused by the reference forward)
    const float* W_ih = (const float*)d_in[2];
    const float* W_hh = (const float*)d_in[3];
    const float* b_ih = (const float*)d_in[4];
    const float* b_hh = (const float*)d_in[5];
    const float* Wp   = (const float*)d_in[6];
    const float* bp   = (const float*)d_in[7];

    float* ws      = (float*)d_ws;
    float* out_b   = (float*)d_out;
    float* out_sel = out_b + (size_t)BS * SEQ;

    // largest T with TWO XP windows fitting in ws
    int T = 0;
    for (int cand = 128; cand >= 8; cand >>= 1) {
        size_t need = ((size_t)M0_XP + 2 * (size_t)cand * BS * GATES) * sizeof(float);
        if (ws_size >= need) { T = cand; break; }
    }

    if (T > 0) {
        hipLaunchKernelGGL((prep_kernel<0>), dim3(FEAT), dim3(GATES), 0, stream,
                           W_ih, W_hh, b_ih, b_hh, ws);
        const int win_f = T * BS * GATES;      // window size in floats
        const int nch = SEQ / T;
        // prologue: window 0
        hipLaunchKernelGGL(xproj_gemm, dim3(GATES / 64, T), dim3(256), 0, stream,
                           x, W_ih, ws, 0, M0_XP);
        for (int c = 0; c < nch; ++c) {
            const int xp_cur = M0_XP + (c & 1) * win_f;
            const int xp_nxt = (c + 1 < nch) ? (M0_XP + ((c + 1) & 1) * win_f) : -1;
            hipLaunchKernelGGL(fused_kernel, dim3(BS + NGEMM), dim3(1024), 0, stream,
                               x, W_ih, ws, Wp, bp, out_b, out_sel,
                               c * T, T, xp_cur, xp_nxt);
        }
    } else {
        hipLaunchKernelGGL((prep_kernel<1>), dim3(FEAT), dim3(GATES), 0, stream,
                           W_ih, W_hh, b_ih, b_hh, ws);
        hipLaunchKernelGGL(consumer1, dim3(BS), dim3(1024), 0, stream,
                           x, ws, Wp, bp, out_b, out_sel);
    }
}

// Round 7
// 11409.856 us; speedup vs baseline: 7.5732x; 1.2141x over previous
//
#include <hip/hip_runtime.h>
#include <cstdint>
#include <cmath>

#define FEAT 256
#define GATES 1024
#define BS 64
#define SEQ 2048
#define NEG_BIG -10000.0f
#define MIN_SEG 3.0f

#define KK_REG 40                 // k-rows per chunk in VGPRs (160 regs/thread)
#define KK_LDS 16                 // k-rows per chunk in LDS (128 KB total)
#define KK_STA (KK_REG + KK_LDS)  // 56 of 128 rows/chunk stationary
#define KPC 128                   // k-rows per chunk (2 chunks x 128 = 256)
#define NGEMM 192                 // gemm-role blocks in fused kernel

// ---- mode0 ws layout (floats) ----
#define M0_WPB  262144            // [1024] W_ih[:,0]
#define M0_BIAS 263168            // [1024] b_ih + b_hh
#define M0_H    264192            // [64][256]
#define M0_C    280576            // [64][256]
#define M0_PF   296960            // [64][2] prev,flag
#define M0_XP   297984            // two [T][64][1024] windows follow
// ---- mode1 fallback layout ----
#define M1_WIT  262144
#define M1_WPB  524288
#define M1_BIAS 525312

// consumer smem layout (floats)
#define S_WLDS 0                  // [32][1024] stationary LDS weights
#define S_PART 32768              // [2][1024]
#define S_XP   34816              // [2][1024]
#define S_H    36864              // [256]
#define S_RED  37120              // [8]
#define S_PV   37128              // [2]
#define S_TOT  37130              // 148.5 KB

template<int MODE>
__global__ __launch_bounds__(1024) void prep_kernel(
    const float* __restrict__ W_ih, const float* __restrict__ W_hh,
    const float* __restrict__ b_ih, const float* __restrict__ b_hh,
    float* __restrict__ ws)
{
    const int k = blockIdx.x;    // 0..255
    const int j = threadIdx.x;   // 0..1023
    ws[k * GATES + j] = W_hh[(size_t)j * FEAT + k];          // WT[k][j]
    if (MODE == 1)
        ws[M1_WIT + k * GATES + j] = W_ih[(size_t)j * (FEAT + 1) + 1 + k];
    if (k == 0) {
        const int WPB = MODE ? M1_WPB : M0_WPB;
        const int BIA = MODE ? M1_BIAS : M0_BIAS;
        ws[WPB + j] = W_ih[(size_t)j * (FEAT + 1)];
        ws[BIA + j] = b_ih[j] + b_hh[j];
    }
    if (MODE == 0 && k == 1) {
#pragma unroll
        for (int i = 0; i < 16; ++i) {
            ws[M0_H + i * 1024 + j] = 0.f;
            ws[M0_C + i * 1024 + j] = 0.f;
        }
        if (j < 128) ws[M0_PF + j] = 0.f;
    }
}

// Prologue GEMM (window 0 only): XP[trow][b][j] = x(t0+trow) @ W_ih[:,1:]^T + bias
__global__ __launch_bounds__(256) void xproj_gemm(
    const float* __restrict__ x, const float* __restrict__ W_ih,
    float* __restrict__ ws, int t0, int xpoff)
{
    const int trow = blockIdx.y;
    const int t  = t0 + trow;
    const int j0 = blockIdx.x * 64;
    const int tid = threadIdx.x;
    const int ty = tid >> 4, tx = tid & 15;
    const float* bias = ws + M0_BIAS;
    float* XP = ws + xpoff;
    __shared__ __align__(16) float As[64][65];
    __shared__ __align__(16) float Bs[64][65];
    float acc[4][4] = {};
    for (int k0 = 0; k0 < FEAT; k0 += 64) {
#pragma unroll
        for (int i = 0; i < 16; ++i) {
            int idx = i * 256 + tid;
            int rr = idx >> 6, cc = idx & 63;
            As[rr][cc] = x[((size_t)rr * SEQ + t) * FEAT + k0 + cc];
        }
#pragma unroll
        for (int i = 0; i < 16; ++i) {
            int idx = i * 256 + tid;
            int jj = idx >> 6, kk = idx & 63;
            Bs[kk][jj] = W_ih[(size_t)(j0 + jj) * (FEAT + 1) + 1 + k0 + kk];
        }
        __syncthreads();
#pragma unroll
        for (int kk = 0; kk < 64; ++kk) {
            float a[4], bv[4];
#pragma unroll
            for (int r = 0; r < 4; ++r) a[r] = As[ty * 4 + r][kk];
#pragma unroll
            for (int c = 0; c < 4; ++c) bv[c] = Bs[kk][tx * 4 + c];
#pragma unroll
            for (int r = 0; r < 4; ++r)
#pragma unroll
                for (int c = 0; c < 4; ++c)
                    acc[r][c] = fmaf(a[r], bv[c], acc[r][c]);
        }
        __syncthreads();
    }
#pragma unroll
    for (int r = 0; r < 4; ++r) {
        int bb = ty * 4 + r;
        size_t base = ((size_t)trow * BS + bb) * GATES + j0 + tx * 4;
        float4 v;
        v.x = acc[r][0] + bias[j0 + tx * 4 + 0];
        v.y = acc[r][1] + bias[j0 + tx * 4 + 1];
        v.z = acc[r][2] + bias[j0 + tx * 4 + 2];
        v.w = acc[r][3] + bias[j0 + tx * 4 + 3];
        *(float4*)&XP[base] = v;
    }
}

#define FMA4(acc, hb, wv) \
    acc.x = fmaf(hb, wv.x, acc.x); acc.y = fmaf(hb, wv.y, acc.y); \
    acc.z = fmaf(hb, wv.z, acc.z); acc.w = fmaf(hb, wv.w, acc.w);

// Heterogeneous kernel, 512 threads/block: blocks 0..63 = recurrence;
// blocks 64..255 = GEMM producing next chunk's XP. Disjoint ws regions;
// kernel boundary is the only producer->consumer sync.
__global__ __launch_bounds__(512, 1) void fused_kernel(
    const float* __restrict__ x, const float* __restrict__ W_ih,
    float* __restrict__ ws,
    const float* __restrict__ Wp, const float* __restrict__ bp,
    float* __restrict__ out_b, float* __restrict__ out_sel,
    int t0, int Tlen, int xp_cur, int xp_nxt)
{
    __shared__ __align__(16) float smem[S_TOT];   // 148.5 KB, overlaid per role
    const int tid = threadIdx.x;

    if (blockIdx.x >= BS) {
        // ================= GEMM role =================
        if (xp_nxt < 0) return;
        float* As = smem;            // [64][65]
        float* Bs = smem + 4160;     // [64][260] (float4-aligned rows)
        const float* bias = ws + M0_BIAS;
        float* XPn = ws + xp_nxt;
        const int tx = tid & 63, ty = tid >> 6;   // ty uniform per wave
        const int jobs = Tlen * 4;                // (trow, j-quarter of 256)
        for (int job = blockIdx.x - BS; job < jobs; job += NGEMM) {
            const int trow = job >> 2;
            const int j0 = (job & 3) * 256;
            const int t = t0 + Tlen + trow;
            float acc[8][4] = {};
            for (int k0 = 0; k0 < FEAT; k0 += 64) {
                __syncthreads();                   // WAR on LDS reuse
#pragma unroll
                for (int i = 0; i < 8; ++i) {
                    int idx = i * 512 + tid, rr = idx >> 6, cc = idx & 63;
                    As[rr * 65 + cc] = x[((size_t)rr * SEQ + t) * FEAT + k0 + cc];
                }
#pragma unroll
                for (int i = 0; i < 32; ++i) {
                    int idx = i * 512 + tid, jj = idx >> 6, kk = idx & 63;
                    Bs[kk * 260 + jj] = W_ih[(size_t)(j0 + jj) * (FEAT + 1) + 1 + k0 + kk];
                }
                __syncthreads();
#pragma unroll 4
                for (int kk = 0; kk < 64; ++kk) {
                    float4 bv = *(const float4*)&Bs[kk * 260 + tx * 4];
#pragma unroll
                    for (int r = 0; r < 8; ++r) {
                        float a = As[(ty * 8 + r) * 65 + kk];
                        acc[r][0] = fmaf(a, bv.x, acc[r][0]);
                        acc[r][1] = fmaf(a, bv.y, acc[r][1]);
                        acc[r][2] = fmaf(a, bv.z, acc[r][2]);
                        acc[r][3] = fmaf(a, bv.w, acc[r][3]);
                    }
                }
            }
#pragma unroll
            for (int r = 0; r < 8; ++r) {
                int bb = ty * 8 + r;
                size_t base = ((size_t)trow * BS + bb) * GATES + j0 + tx * 4;
                float4 v;
                v.x = acc[r][0] + bias[j0 + tx * 4 + 0];
                v.y = acc[r][1] + bias[j0 + tx * 4 + 1];
                v.z = acc[r][2] + bias[j0 + tx * 4 + 2];
                v.w = acc[r][3] + bias[j0 + tx * 4 + 3];
                *(float4*)&XPn[base] = v;
            }
        }
        return;
    }

    // ================= consumer role =================
    const int b   = blockIdx.x;
    const int ch  = tid >> 8;          // k-chunk 0..1 (128 k-rows each)
    const int j4  = (tid & 255) * 4;   // gate quad
    const int f   = tid & 255;         // feature (phase-2 role, tid<256)
    const int kbase = ch * KPC;

    const float* WT  = ws;
    const float* WPB = ws + M0_WPB;
    float* H  = ws + M0_H;
    float* C  = ws + M0_C;
    float* PF = ws + M0_PF;
    const float* XPc = ws + xp_cur;

    float* wlds   = smem + S_WLDS;
    float* part   = smem + S_PART;
    float* xp_lds = smem + S_XP;
    float* h_lds  = smem + S_H;
    float* red    = smem + S_RED;
    float* s_pv   = smem + S_PV;

    // stationary weights: registers (40 float4 = 160 VGPR/thread = 320 KB/block)
    float4 wreg[KK_REG];
#pragma unroll
    for (int kk = 0; kk < KK_REG; ++kk)
        wreg[kk] = *(const float4*)&WT[(size_t)(kbase + kk) * GATES + j4];
    // stationary weights: LDS (rows KK_REG..KK_STA-1 of each chunk, 128 KB)
#pragma unroll
    for (int i = 0; i < 64; ++i) {
        int idx = i * 512 + tid;
        int row = idx >> 10, col = idx & 1023;
        int ch2 = row >> 4, kkl = row & 15;
        wlds[row * 1024 + col] = WT[(size_t)(ch2 * KPC + KK_REG + kkl) * GATES + col];
    }

    float wpbr[4] = {};
    float wp0 = 0.f, wp1 = 0.f, c_reg = 0.f;
    if (tid < FEAT) {
#pragma unroll
        for (int g = 0; g < 4; ++g) wpbr[g] = WPB[g * FEAT + f];
        wp0 = Wp[f]; wp1 = Wp[FEAT + f];
        c_reg = C[b * FEAT + f];
        h_lds[f] = H[b * FEAT + f];
    }
    const float bp0 = bp[0], bp1 = bp[1];
    xp_lds[tid]       = XPc[(size_t)b * GATES + tid];         // window row 0
    xp_lds[tid + 512] = XPc[(size_t)b * GATES + tid + 512];
    if (tid == 0) { s_pv[0] = PF[b * 2 + 0]; s_pv[1] = PF[b * 2 + 1]; }
    __syncthreads();

    float fl_r = 0.f;
    if (tid == 0) fl_r = s_pv[1];

    for (int tl = 0; tl < Tlen; ++tl) {
        const int t   = t0 + tl;
        const int buf = tl & 1;

        // prefetch next step's xp row (2 floats/thread)
        float xpf0 = 0.f, xpf1 = 0.f;
        const bool haspf = (tl + 1 < Tlen);
        if (haspf) {
            const float* xr = XPc + ((size_t)(tl + 1) * BS + b) * GATES;
            xpf0 = xr[tid]; xpf1 = xr[tid + 512];
        }

        // ---- phase 1: gate matvec (all 8 waves) ----
        float4 acc = make_float4(0.f, 0.f, 0.f, 0.f);
#pragma unroll
        for (int kk = 0; kk < KK_REG; ++kk) {
            float hb = h_lds[kbase + kk];
            FMA4(acc, hb, wreg[kk]);
        }
#pragma unroll
        for (int kk = 0; kk < KK_LDS; ++kk) {
            float hb = h_lds[kbase + KK_REG + kk];
            float4 wv = *(const float4*)&wlds[(ch * KK_LDS + kk) * 1024 + j4];
            FMA4(acc, hb, wv);
        }
#pragma unroll 8
        for (int kk = KK_STA; kk < KPC; ++kk) {
            float hb = h_lds[kbase + kk];
            float4 wv = *(const float4*)&WT[(size_t)(kbase + kk) * GATES + j4];
            FMA4(acc, hb, wv);
        }
        *(float4*)&part[ch * 1024 + j4] = acc;
        __syncthreads();                                     // A

        if (haspf) {
            xp_lds[(buf ^ 1) * 1024 + tid]       = xpf0;
            xp_lds[(buf ^ 1) * 1024 + tid + 512] = xpf1;
        }

        // ---- phase 2: gate combine + LSTM + policy (threads 0..255) ----
        if (tid < FEAT) {
            const float pvv = s_pv[0];
            float gv[4];
#pragma unroll
            for (int g = 0; g < 4; ++g) {
                const int jj = g * FEAT + f;
                gv[g] = part[jj] + part[1024 + jj]
                      + xp_lds[buf * 1024 + jj] + pvv * wpbr[g];
            }
            float ig = 1.f / (1.f + expf(-gv[0]));
            float fg = 1.f / (1.f + expf(-gv[1]));
            float gt = tanhf(gv[2]);
            float og = 1.f / (1.f + expf(-gv[3]));
            c_reg = fg * c_reg + ig * gt;
            float h = og * tanhf(c_reg);
            h_lds[f] = h;
            if (tl == Tlen - 1) {
                H[b * FEAT + f] = h;
                C[b * FEAT + f] = c_reg;
            }
            float p0 = h * wp0, p1 = h * wp1;
#pragma unroll
            for (int off = 32; off > 0; off >>= 1) {
                p0 += __shfl_xor(p0, off, 64);
                p1 += __shfl_xor(p1, off, 64);
            }
            if ((tid & 63) == 0) {
                red[tid >> 6] = p0;
                red[4 + (tid >> 6)] = p1;
            }
        }
        __syncthreads();                                     // B

        // ---- phase 3: decision (tid 0); s_pv consumers are behind barrier A
        // of step t+1 (proven pattern).
        if (tid == 0) {
            float l0 = red[0] + red[1] + red[2] + red[3] + bp0;
            float l1 = red[4] + red[5] + red[6] + red[7] + bp1;
            if (fl_r > 0.0f) l1 += NEG_BIG;
            int samp = (l1 > l0) ? 1 : 0;
            float a0 = l0 * 0.5f, a1 = l1 * 0.5f;   // logits / TAU, TAU = 2
            float m = fmaxf(a0, a1);
            float lse = m + logf(expf(a0 - m) + expf(a1 - m));
            out_b[(size_t)b * SEQ + t]   = (float)samp;
            out_sel[(size_t)b * SEQ + t] = (samp ? a1 : a0) - lse;
            fl_r = (fl_r > 0.0f) ? (fl_r - 1.0f) : fl_r;
            if (samp) fl_r = MIN_SEG;
            s_pv[0] = (float)samp;
            if (tl == Tlen - 1) {
                PF[b * 2 + 0] = (float)samp;
                PF[b * 2 + 1] = fl_r;
            }
        }
    }
}

// ---- mode1 fallback (tiny ws): fused streaming consumer (r5-proven) ----
__global__ __launch_bounds__(1024) void consumer1(
    const float* __restrict__ x, float* __restrict__ ws,
    const float* __restrict__ Wp, const float* __restrict__ bp,
    float* __restrict__ out_b, float* __restrict__ out_sel)
{
    const int b   = blockIdx.x;
    const int tid = threadIdx.x;
    const int ch  = tid >> 8;
    const int j4  = (tid & 255) * 4;
    const int f   = tid & 255;
    const int kbase = ch * 64;

    const float* WT   = ws;
    const float* WIT  = ws + M1_WIT;
    const float* WPB  = ws + M1_WPB;
    const float* BIAS = ws + M1_BIAS;

    __shared__ __align__(16) float part[4][GATES];
    __shared__ __align__(16) float h_lds[FEAT];
    __shared__ __align__(16) float x_lds[2][FEAT];
    __shared__ float red[8];
    __shared__ float s_pv[2];

    float biasr[4] = {}, wpbr[4] = {};
    float wp0 = 0.f, wp1 = 0.f, c_reg = 0.f;
    if (tid < FEAT) {
#pragma unroll
        for (int g = 0; g < 4; ++g) {
            wpbr[g]  = WPB[g * FEAT + f];
            biasr[g] = BIAS[g * FEAT + f];
        }
        wp0 = Wp[f]; wp1 = Wp[FEAT + f];
        h_lds[f] = 0.f;
        x_lds[0][f] = x[(size_t)b * SEQ * FEAT + f];
    }
    const float bp0 = bp[0], bp1 = bp[1];
    if (tid == 0) { s_pv[0] = 0.f; s_pv[1] = 0.f; }
    __syncthreads();

    float fl_r = 0.f;
    for (int t = 0; t < SEQ; ++t) {
        const int buf = t & 1;
        float xpf = 0.f;
        const bool haspf = (t + 1 < SEQ) && (tid < FEAT);
        if (haspf) xpf = x[((size_t)b * SEQ + (t + 1)) * FEAT + f];

        float4 acc = make_float4(0.f, 0.f, 0.f, 0.f);
#pragma unroll 4
        for (int kk = 0; kk < 64; ++kk) {
            float hb = h_lds[kbase + kk];
            float4 wv = *(const float4*)&WT[(size_t)(kbase + kk) * GATES + j4];
            FMA4(acc, hb, wv);
            float xb = x_lds[buf][kbase + kk];
            float4 wi = *(const float4*)&WIT[(size_t)(kbase + kk) * GATES + j4];
            FMA4(acc, xb, wi);
        }
        *(float4*)&part[ch][j4] = acc;
        __syncthreads();
        if (haspf) x_lds[buf ^ 1][f] = xpf;

        if (tid < FEAT) {
            const float pvv = s_pv[0];
            float gv[4];
#pragma unroll
            for (int g = 0; g < 4; ++g) {
                const int jj = g * FEAT + f;
                gv[g] = part[0][jj] + part[1][jj] + part[2][jj] + part[3][jj]
                      + biasr[g] + pvv * wpbr[g];
            }
            float ig = 1.f / (1.f + expf(-gv[0]));
            float fg = 1.f / (1.f + expf(-gv[1]));
            float gt = tanhf(gv[2]);
            float og = 1.f / (1.f + expf(-gv[3]));
            c_reg = fg * c_reg + ig * gt;
            float h = og * tanhf(c_reg);
            h_lds[f] = h;
            float p0 = h * wp0, p1 = h * wp1;
#pragma unroll
            for (int off = 32; off > 0; off >>= 1) {
                p0 += __shfl_xor(p0, off, 64);
                p1 += __shfl_xor(p1, off, 64);
            }
            if ((tid & 63) == 0) { red[tid >> 6] = p0; red[4 + (tid >> 6)] = p1; }
        }
        __syncthreads();

        if (tid == 0) {
            float l0 = red[0] + red[1] + red[2] + red[3] + bp0;
            float l1 = red[4] + red[5] + red[6] + red[7] + bp1;
            if (fl_r > 0.0f) l1 += NEG_BIG;
            int samp = (l1 > l0) ? 1 : 0;
            float a0 = l0 * 0.5f, a1 = l1 * 0.5f;
            float m = fmaxf(a0, a1);
            float lse = m + logf(expf(a0 - m) + expf(a1 - m));
            out_b[(size_t)b * SEQ + t]   = (float)samp;
            out_sel[(size_t)b * SEQ + t] = (samp ? a1 : a0) - lse;
            fl_r = (fl_r > 0.0f) ? (fl_r - 1.0f) : fl_r;
            if (samp) fl_r = MIN_SEG;
            s_pv[0] = (float)samp;
        }
    }
}

extern "C" void kernel_launch(void* const* d_in, const int* in_sizes, int n_in,
                              void* d_out, int out_size, void* d_ws, size_t ws_size,
                              hipStream_t stream)
{
    const float* x    = (const float*)d_in[0];
    // d_in[1] = label (unused by the reference forward)
    const float* W_ih = (const float*)d_in[2];
    const float* W_hh = (const float*)d_in[3];
    const float* b_ih = (const float*)d_in[4];
    const float* b_hh = (const float*)d_in[5];
    const float* Wp   = (const float*)d_in[6];
    const float* bp   = (const float*)d_in[7];

    float* ws      = (float*)d_ws;
    float* out_b   = (float*)d_out;
    float* out_sel = out_b + (size_t)BS * SEQ;

    // largest T with TWO XP windows fitting in ws
    int T = 0;
    for (int cand = 128; cand >= 8; cand >>= 1) {
        size_t need = ((size_t)M0_XP + 2 * (size_t)cand * BS * GATES) * sizeof(float);
        if (ws_size >= need) { T = cand; break; }
    }

    if (T > 0) {
        hipLaunchKernelGGL((prep_kernel<0>), dim3(FEAT), dim3(GATES), 0, stream,
                           W_ih, W_hh, b_ih, b_hh, ws);
        const int win_f = T * BS * GATES;
        const int nch = SEQ / T;
        hipLaunchKernelGGL(xproj_gemm, dim3(GATES / 64, T), dim3(256), 0, stream,
                           x, W_ih, ws, 0, M0_XP);
        for (int c = 0; c < nch; ++c) {
            const int xp_cur = M0_XP + (c & 1) * win_f;
            const int xp_nxt = (c + 1 < nch) ? (M0_XP + ((c + 1) & 1) * win_f) : -1;
            hipLaunchKernelGGL(fused_kernel, dim3(BS + NGEMM), dim3(512), 0, stream,
                               x, W_ih, ws, Wp, bp, out_b, out_sel,
                               c * T, T, xp_cur, xp_nxt);
        }
    } else {
        hipLaunchKernelGGL((prep_kernel<1>), dim3(FEAT), dim3(GATES), 0, stream,
                           W_ih, W_hh, b_ih, b_hh, ws);
        hipLaunchKernelGGL(consumer1, dim3(BS), dim3(1024), 0, stream,
                           x, ws, Wp, bp, out_b, out_sel);
    }
}